// Round 4
// baseline (1172.863 us; speedup 1.0000x reference)
//
#include <hip/hip_runtime.h>
#include <hip/hip_bf16.h>
#include <math.h>

#define N_ATOMS 8192
#define N_EDGES 262144
#define N_MOL   128
#define FDIM    128
#define RDIM    20
#define LLAYERS 3
#define CUTOFF  5.0f
#define EPSV    1e-8f
#define PI_F    3.14159265358979323846f

// ---------------- embed gather ----------------
__global__ void k_embed(const int* __restrict__ z, const float* __restrict__ embed,
                        float* __restrict__ S) {
    int i = blockIdx.x * 256 + threadIdx.x;           // over 8192*128
    int a = i >> 7, k = i & 127;
    S[i] = embed[(size_t)z[a] * FDIM + k];
}

// ---------------- edge geometry + rbf ----------------
__global__ void k_edges(const float* __restrict__ pos, const int* __restrict__ esrc,
                        const int* __restrict__ edst, float* __restrict__ RBF,
                        float* __restrict__ UNITFC) {
    int e = blockIdx.x * 256 + threadIdx.x;
    if (e >= N_EDGES) return;
    int s = esrc[e], d = edst[e];
    float rx = pos[d*3+0] - pos[s*3+0];
    float ry = pos[d*3+1] - pos[s*3+1];
    float rz = pos[d*3+2] - pos[s*3+2];
    float dd = sqrtf(rx*rx + ry*ry + rz*rz + EPSV);
    float inv = 1.0f / dd;
    float fc = (dd < CUTOFF) ? 0.5f * (cosf(dd * (PI_F / CUTOFF)) + 1.0f) : 0.0f;
    float4 u4; u4.x = rx*inv; u4.y = ry*inv; u4.z = rz*inv; u4.w = fc;
    *(float4*)&UNITFC[(size_t)e*4] = u4;
    #pragma unroll
    for (int r = 0; r < RDIM; r++) {
        float freq = (float)(r + 1) * (PI_F / CUTOFF);
        RBF[(size_t)e*RDIM + r] = sinf(dd * freq) * inv;
    }
}

// ---------------- CSR build ----------------
__global__ void k_hist(const int* __restrict__ edst, int* __restrict__ CNT) {
    int e = blockIdx.x * 256 + threadIdx.x;
    if (e < N_EDGES) atomicAdd(&CNT[edst[e]], 1);
}

__global__ __launch_bounds__(1024) void k_scan(const int* __restrict__ CNT,
                                               int* __restrict__ OFF, int* __restrict__ CUR) {
    __shared__ int part[1024];
    int t = threadIdx.x;
    int loc[8];
    int run = 0;
    #pragma unroll
    for (int i = 0; i < 8; i++) { int c = CNT[t*8 + i]; loc[i] = run; run += c; }
    part[t] = run;
    __syncthreads();
    for (int off = 1; off < 1024; off <<= 1) {
        int v = 0;
        if (t >= off) v = part[t - off];
        __syncthreads();
        part[t] += v;
        __syncthreads();
    }
    int ebase = (t > 0) ? part[t-1] : 0;
    #pragma unroll
    for (int i = 0; i < 8; i++) { int o = ebase + loc[i]; OFF[t*8+i] = o; CUR[t*8+i] = o; }
    if (t == 1023) OFF[8192] = part[1023];
}

__global__ void k_fill(const int* __restrict__ edst, int* __restrict__ CUR,
                       int* __restrict__ EIDX) {
    int e = blockIdx.x * 256 + threadIdx.x;
    if (e < N_EDGES) {
        int p = atomicAdd(&CUR[edst[e]], 1);
        EIDX[p] = e;
    }
}

// ---------------- GEMM v2: 32x64 tile, BK=32, double-buffered ----------------
// C = act(Asplit @ Bsel + bias). A row-major (M,K) split at asplit into [A|A2].
// B row-major (K,N); column-block bn selects (B,bias,C,ldc) vs (B2,bias2,C2,ldc2)
// at column bsplit (per-block uniform; 64 | bsplit required).
template<bool SILU>
__global__ __launch_bounds__(256) void k_gemm2(
    const float* __restrict__ A, int lda, const float* __restrict__ A2, int lda2, int asplit,
    const float* __restrict__ B, int ldb, const float* __restrict__ B2, int ldb2, int bsplit,
    const float* __restrict__ bias, const float* __restrict__ bias2,
    float* __restrict__ C, int ldc, float* __restrict__ C2, int ldc2,
    int M, int N, int K)
{
    __shared__ float As[2][32][34];
    __shared__ float Bs[2][32][64];
    int tid = threadIdx.x;
    int bm = blockIdx.y * 32;
    int bn = blockIdx.x * 64;

    const float* Bp; int ldb_; const float* biasp; float* Cp; int ldc_; int cb;
    if (bn < bsplit) { Bp = B;  ldb_ = ldb;  biasp = bias;  Cp = C;  ldc_ = ldc;  cb = bn; }
    else             { Bp = B2; ldb_ = ldb2; biasp = bias2; Cp = C2; ldc_ = ldc2; cb = bn - bsplit; }

    int arow  = tid >> 3;           // 0..31
    int akseg = (tid & 7) * 4;      // 0,4,...,28
    int bkr   = tid >> 4;           // 0..15
    int bcol  = (tid & 15) * 4;     // 0..60
    int tx = tid & 15, ty = tid >> 4;

    float4 aR, bR0, bR1;
    auto loadTile = [&](int k0) {
        int kl = k0 + akseg;
        const float* Ap; int ldA;
        if (kl < asplit) { Ap = A; ldA = lda; } else { Ap = A2; ldA = lda2; kl -= asplit; }
        aR  = *(const float4*)&Ap[(size_t)(bm + arow) * ldA + kl];
        bR0 = *(const float4*)&Bp[(size_t)(k0 + bkr)      * ldb_ + cb + bcol];
        bR1 = *(const float4*)&Bp[(size_t)(k0 + bkr + 16) * ldb_ + cb + bcol];
    };
    auto storeTile = [&](int c) {
        As[c][akseg+0][arow] = aR.x;
        As[c][akseg+1][arow] = aR.y;
        As[c][akseg+2][arow] = aR.z;
        As[c][akseg+3][arow] = aR.w;
        *(float4*)&Bs[c][bkr][bcol]      = bR0;
        *(float4*)&Bs[c][bkr + 16][bcol] = bR1;
    };

    float acc[2][4] = {{0.f,0.f,0.f,0.f},{0.f,0.f,0.f,0.f}};
    loadTile(0);
    storeTile(0);
    int steps = K >> 5;
    for (int s = 0; s < steps; s++) {
        int c = s & 1;
        __syncthreads();
        if (s + 1 < steps) loadTile((s + 1) << 5);
        #pragma unroll
        for (int kk = 0; kk < 32; kk++) {
            float2 a2v = *(const float2*)&As[c][kk][ty*2];
            float4 b4  = *(const float4*)&Bs[c][kk][tx*4];
            acc[0][0] += a2v.x*b4.x; acc[0][1] += a2v.x*b4.y;
            acc[0][2] += a2v.x*b4.z; acc[0][3] += a2v.x*b4.w;
            acc[1][0] += a2v.y*b4.x; acc[1][1] += a2v.y*b4.y;
            acc[1][2] += a2v.y*b4.z; acc[1][3] += a2v.y*b4.w;
        }
        if (s + 1 < steps) storeTile(1 - c);
    }
    #pragma unroll
    for (int i = 0; i < 2; i++) {
        int m = bm + ty*2 + i;
        float4 o;
        float* op = &o.x;
        #pragma unroll
        for (int j = 0; j < 4; j++) {
            float val = acc[i][j] + (biasp ? biasp[cb + tx*4 + j] : 0.0f);
            if (SILU) val = val / (1.0f + __expf(-val));
            op[j] = val;
        }
        *(float4*)&Cp[(size_t)m * ldc_ + cb + tx*4] = o;
    }
}

// ---------------- edge aggregation: 3 wave-groups, LDS-staged edge list ----------------
__global__ __launch_bounds__(384) void k_aggregate(
    const float* __restrict__ PHI, const float* __restrict__ vin,
    float* __restrict__ S, float* __restrict__ vout,
    const float* __restrict__ RBF, const float* __restrict__ UNITFC,
    const int* __restrict__ esrc, const int* __restrict__ OFF, const int* __restrict__ EIDX,
    const float* __restrict__ rbfw, const float* __restrict__ rbfb)
{
    int a = blockIdx.x;
    int tid = threadIdx.x;
    int g = tid >> 7;        // wave-uniform group: 0=ds, 1=v*dvv, 2=unit*dvs
    int t = tid & 127;

    float w[RDIM];
    const float* wcol = rbfw + g*128 + t;
    #pragma unroll
    for (int r = 0; r < RDIM; r++) w[r] = wcol[r*384];
    float bb = rbfb[g*128 + t];

    __shared__ int sE[128], sSrc[128];
    __shared__ float avs[3][128];

    int beg = OFF[a], end = OFF[a + 1];
    float accs = 0.f, av0 = 0.f, av1 = 0.f, av2 = 0.f;

    for (int p0 = beg; p0 < end; p0 += 128) {
        int n = end - p0; if (n > 128) n = 128;
        if (tid < n) { int e = EIDX[p0 + tid]; sE[tid] = e; sSrc[tid] = esrc[e]; }
        __syncthreads();
        for (int q = 0; q < n; q++) {
            int e = sE[q], src = sSrc[q];
            const float4* rb4 = (const float4*)(RBF + (size_t)e * RDIM);
            float4 r0 = rb4[0], r1 = rb4[1], r2 = rb4[2], r3 = rb4[3], r4 = rb4[4];
            float4 ufc = *(const float4*)(UNITFC + (size_t)e * 4);
            float ph = PHI[(size_t)src * 384 + g*128 + t];
            float f = bb;
            f += r0.x*w[0]  + r0.y*w[1]  + r0.z*w[2]  + r0.w*w[3];
            f += r1.x*w[4]  + r1.y*w[5]  + r1.z*w[6]  + r1.w*w[7];
            f += r2.x*w[8]  + r2.y*w[9]  + r2.z*w[10] + r2.w*w[11];
            f += r3.x*w[12] + r3.y*w[13] + r3.z*w[14] + r3.w*w[15];
            f += r4.x*w[16] + r4.y*w[17] + r4.z*w[18] + r4.w*w[19];
            float m = ph * (f * ufc.w);
            if (g == 0) {
                accs += m;
            } else if (g == 1) {
                const float* vs = vin + (size_t)src * 384 + t;
                av0 += vs[0]   * m;
                av1 += vs[128] * m;
                av2 += vs[256] * m;
            } else {
                av0 += ufc.x * m;
                av1 += ufc.y * m;
                av2 += ufc.z * m;
            }
        }
        __syncthreads();
    }

    if (g == 1) { avs[0][t] = av0; avs[1][t] = av1; avs[2][t] = av2; }
    __syncthreads();
    if (g == 0) {
        S[(size_t)a * 128 + t] += accs;
    } else if (g == 2) {
        size_t vb = (size_t)a * 384 + t;
        vout[vb]       = vin[vb]       + avs[0][t] + av0;
        vout[vb + 128] = vin[vb + 128] + avs[1][t] + av1;
        vout[vb + 256] = vin[vb + 256] + avs[2][t] + av2;
    }
}

// ---------------- vv-norm + <uv,vv> ----------------
__global__ void k_vvdot(const float* __restrict__ UV, const float* __restrict__ VV,
                        float* __restrict__ VVN, float* __restrict__ DOT) {
    int i = blockIdx.x * 256 + threadIdx.x;           // over 8192*128
    int a = i >> 7, k = i & 127;
    size_t b = (size_t)a * 384 + k;
    float u0 = UV[b], u1 = UV[b+128], u2 = UV[b+256];
    float v0 = VV[b], v1 = VV[b+128], v2 = VV[b+256];
    VVN[i] = sqrtf(v0*v0 + v1*v1 + v2*v2 + EPSV);
    DOT[i] = u0*v0 + u1*v1 + u2*v2;
}

// ---------------- s,v update epilogue ----------------
__global__ void k_update(float* __restrict__ S, float* __restrict__ v,
                         const float* __restrict__ Abuf, const float* __restrict__ UV,
                         const float* __restrict__ DOT) {
    int i = blockIdx.x * 256 + threadIdx.x;           // over 8192*128
    int a = i >> 7, k = i & 127;
    size_t b = (size_t)a * 384 + k;
    float a_vv = Abuf[b], a_sv = Abuf[b+128], a_ss = Abuf[b+256];
    S[i] += a_ss + a_sv * DOT[i];
    v[b]       += a_vv * UV[b];
    v[b + 128] += a_vv * UV[b + 128];
    v[b + 256] += a_vv * UV[b + 256];
}

// ---------------- readout dot: AOUT[a] = H[a,:] . w2 + b2 ----------------
__global__ __launch_bounds__(256) void k_dot(const float* __restrict__ H,
                                             const float* __restrict__ w2,
                                             const float* __restrict__ b2v,
                                             float* __restrict__ AOUT) {
    int lane = threadIdx.x & 63;
    int wv = threadIdx.x >> 6;
    int a = blockIdx.x * 4 + wv;
    const float* h = &H[(size_t)a * 128];
    float p = h[lane] * w2[lane] + h[64 + lane] * w2[64 + lane];
    #pragma unroll
    for (int off = 32; off > 0; off >>= 1) p += __shfl_down(p, off);
    if (lane == 0) AOUT[a] = p + b2v[0];
}

// ---------------- per-molecule sum (parallel) ----------------
__global__ void k_molsum(const float* __restrict__ AOUT, const int* __restrict__ mol,
                         float* __restrict__ out) {
    __shared__ float acc[N_MOL];
    int t = threadIdx.x;
    if (t < N_MOL) acc[t] = 0.f;
    __syncthreads();
    for (int i = blockIdx.x * 256 + t; i < N_ATOMS; i += 256 * 32)
        atomicAdd(&acc[mol[i]], AOUT[i]);
    __syncthreads();
    if (t < N_MOL) atomicAdd(&out[t], acc[t]);
}

extern "C" void kernel_launch(void* const* d_in, const int* in_sizes, int n_in,
                              void* d_out, int out_size, void* d_ws, size_t ws_size,
                              hipStream_t stream) {
    const int*   z      = (const int*)d_in[0];
    const float* pos    = (const float*)d_in[1];
    const int*   esrc   = (const int*)d_in[2];
    const int*   edst   = (const int*)d_in[3];
    const int*   mol    = (const int*)d_in[4];
    const float* embed  = (const float*)d_in[5];
    const float* msg_w1 = (const float*)d_in[6];
    const float* msg_b1 = (const float*)d_in[7];
    const float* msg_w2 = (const float*)d_in[8];
    const float* msg_b2 = (const float*)d_in[9];
    const float* rbf_w  = (const float*)d_in[10];
    const float* rbf_b  = (const float*)d_in[11];
    const float* upd_u  = (const float*)d_in[12];
    const float* upd_v  = (const float*)d_in[13];
    const float* upd_a1 = (const float*)d_in[14];
    const float* upd_a1b= (const float*)d_in[15];
    const float* upd_a2 = (const float*)d_in[16];
    const float* upd_a2b= (const float*)d_in[17];
    const float* out_w1 = (const float*)d_in[18];
    const float* out_b1 = (const float*)d_in[19];
    const float* out_w2 = (const float*)d_in[20];
    const float* out_b2 = (const float*)d_in[21];

    float* ws = (float*)d_ws;
    float* S      = ws; ws += 1048576;     // 8192*128
    float* Va     = ws; ws += 3145728;     // 8192*3*128
    float* Vb     = ws; ws += 3145728;
    float* PHI    = ws; ws += 3145728;     // phi / VV / a-output (disjoint lifetimes)
    float* RBF    = ws; ws += 5242880;     // 262144*20
    float* UNITFC = ws; ws += 1048576;     // 262144*4 (ux,uy,uz,fc)
    float* UV     = ws; ws += 3145728;
    float* VVN    = ws; ws += 1048576;
    float* DOT    = ws; ws += 1048576;
    float* H      = ws; ws += 1048576;
    float* AOUT   = ws; ws += 8192;
    int* CNT  = (int*)ws;
    int* OFF  = CNT + 8192;
    int* CUR  = OFF + 8193;
    int* EIDX = CUR + 8192;
    float* VV = PHI;   // lifetime-disjoint alias

    hipMemsetAsync(Va, 0, 3145728 * sizeof(float), stream);
    hipMemsetAsync(CNT, 0, 8192 * sizeof(int), stream);

    k_embed<<<4096, 256, 0, stream>>>(z, embed, S);
    k_edges<<<1024, 256, 0, stream>>>(pos, esrc, edst, RBF, UNITFC);
    k_hist<<<1024, 256, 0, stream>>>(edst, CNT);
    k_scan<<<1, 1024, 0, stream>>>(CNT, OFF, CUR);
    k_fill<<<1024, 256, 0, stream>>>(edst, CUR, EIDX);

    for (int l = 0; l < LLAYERS; l++) {
        const float* vin_ = (l & 1) ? Vb : Va;
        float*       vout_= (l & 1) ? Va : Vb;
        const float* mw1 = msg_w1 + (size_t)l*128*128;
        const float* mw2 = msg_w2 + (size_t)l*128*384;
        const float* uu  = upd_u  + (size_t)l*128*128;
        const float* uv_ = upd_v  + (size_t)l*128*128;
        const float* a1  = upd_a1 + (size_t)l*256*128;
        const float* a2  = upd_a2 + (size_t)l*128*384;

        // H = silu(S@w1+b1)
        k_gemm2<true><<<dim3(2, 256), 256, 0, stream>>>(
            S, 128, nullptr, 0, 128, mw1, 128, nullptr, 0, 128,
            msg_b1 + (size_t)l*128, nullptr, H, 128, nullptr, 0, 8192, 128, 128);
        // PHI = H@w2+b2
        k_gemm2<false><<<dim3(6, 256), 256, 0, stream>>>(
            H, 128, nullptr, 0, 128, mw2, 384, nullptr, 0, 384,
            msg_b2 + (size_t)l*384, nullptr, PHI, 384, nullptr, 0, 8192, 384, 128);
        // message aggregation
        k_aggregate<<<8192, 384, 0, stream>>>(PHI, vin_, S, vout_, RBF, UNITFC,
            esrc, OFF, EIDX, rbf_w + (size_t)l*20*384, rbf_b + (size_t)l*384);
        // UV | VV in one call (B/C column split at 128)
        k_gemm2<false><<<dim3(4, 768), 256, 0, stream>>>(
            vout_, 128, nullptr, 0, 128, uu, 128, uv_, 128, 128,
            nullptr, nullptr, UV, 128, VV, 128, 24576, 256, 128);
        k_vvdot<<<4096, 256, 0, stream>>>(UV, VV, VVN, DOT);
        // H = silu([S|VVN]@a1+b1)   (A split at K=128)
        k_gemm2<true><<<dim3(2, 256), 256, 0, stream>>>(
            S, 128, VVN, 128, 128, a1, 128, nullptr, 0, 128,
            upd_a1b + (size_t)l*128, nullptr, H, 128, nullptr, 0, 8192, 128, 256);
        // a-out (into PHI) = H@a2+b2
        k_gemm2<false><<<dim3(6, 256), 256, 0, stream>>>(
            H, 128, nullptr, 0, 128, a2, 384, nullptr, 0, 384,
            upd_a2b + (size_t)l*384, nullptr, PHI, 384, nullptr, 0, 8192, 384, 128);
        k_update<<<4096, 256, 0, stream>>>(S, vout_, PHI, UV, DOT);
    }

    // readout: H = silu(S@out_w1+b1); AOUT = H.w2+b2; molecule sum
    k_gemm2<true><<<dim3(2, 256), 256, 0, stream>>>(
        S, 128, nullptr, 0, 128, out_w1, 128, nullptr, 0, 128,
        out_b1, nullptr, H, 128, nullptr, 0, 8192, 128, 128);
    k_dot<<<2048, 256, 0, stream>>>(H, out_w2, out_b2, AOUT);
    hipMemsetAsync(d_out, 0, N_MOL * sizeof(float), stream);
    k_molsum<<<32, 256, 0, stream>>>(AOUT, mol, (float*)d_out);
}

// Round 5
// 1106.200 us; speedup vs baseline: 1.0603x; 1.0603x over previous
//
#include <hip/hip_runtime.h>
#include <hip/hip_bf16.h>
#include <math.h>

#define N_ATOMS 8192
#define N_EDGES 262144
#define N_MOL   128
#define FDIM    128
#define RDIM    20
#define LLAYERS 3
#define CUTOFF  5.0f
#define EPSV    1e-8f
#define PI_F    3.14159265358979323846f

__device__ __forceinline__ ushort f2bf(float x) {
    uint b = __float_as_uint(x);
    return (ushort)((b + 0x7fffu + ((b >> 16) & 1u)) >> 16);
}

// ---------------- embed gather ----------------
__global__ void k_embed(const int* __restrict__ z, const float* __restrict__ embed,
                        float* __restrict__ S) {
    int i = blockIdx.x * 256 + threadIdx.x;           // over 8192*128
    int a = i >> 7, k = i & 127;
    S[i] = embed[(size_t)z[a] * FDIM + k];
}

// ---------------- edge geometry + rbf ----------------
__global__ void k_edges(const float* __restrict__ pos, const int* __restrict__ esrc,
                        const int* __restrict__ edst, float* __restrict__ RBF,
                        float* __restrict__ UNITFC) {
    int e = blockIdx.x * 256 + threadIdx.x;
    if (e >= N_EDGES) return;
    int s = esrc[e], d = edst[e];
    float rx = pos[d*3+0] - pos[s*3+0];
    float ry = pos[d*3+1] - pos[s*3+1];
    float rz = pos[d*3+2] - pos[s*3+2];
    float dd = sqrtf(rx*rx + ry*ry + rz*rz + EPSV);
    float inv = 1.0f / dd;
    float fc = (dd < CUTOFF) ? 0.5f * (cosf(dd * (PI_F / CUTOFF)) + 1.0f) : 0.0f;
    float4 u4; u4.x = rx*inv; u4.y = ry*inv; u4.z = rz*inv; u4.w = fc;
    *(float4*)&UNITFC[(size_t)e*4] = u4;
    #pragma unroll
    for (int r = 0; r < RDIM; r++) {
        float freq = (float)(r + 1) * (PI_F / CUTOFF);
        RBF[(size_t)e*RDIM + r] = sinf(dd * freq) * inv;
    }
}

// ---------------- CSR build ----------------
__global__ void k_hist(const int* __restrict__ edst, int* __restrict__ CNT) {
    int e = blockIdx.x * 256 + threadIdx.x;
    if (e < N_EDGES) atomicAdd(&CNT[edst[e]], 1);
}

__global__ __launch_bounds__(1024) void k_scan(const int* __restrict__ CNT,
                                               int* __restrict__ OFF, int* __restrict__ CUR) {
    __shared__ int part[1024];
    int t = threadIdx.x;
    int loc[8];
    int run = 0;
    #pragma unroll
    for (int i = 0; i < 8; i++) { int c = CNT[t*8 + i]; loc[i] = run; run += c; }
    part[t] = run;
    __syncthreads();
    for (int off = 1; off < 1024; off <<= 1) {
        int v = 0;
        if (t >= off) v = part[t - off];
        __syncthreads();
        part[t] += v;
        __syncthreads();
    }
    int ebase = (t > 0) ? part[t-1] : 0;
    #pragma unroll
    for (int i = 0; i < 8; i++) { int o = ebase + loc[i]; OFF[t*8+i] = o; CUR[t*8+i] = o; }
    if (t == 1023) OFF[8192] = part[1023];
}

__global__ void k_fill(const int* __restrict__ edst, int* __restrict__ CUR,
                       int* __restrict__ EIDX) {
    int e = blockIdx.x * 256 + threadIdx.x;
    if (e < N_EDGES) {
        int p = atomicAdd(&CUR[edst[e]], 1);
        EIDX[p] = e;
    }
}

// ---------------- GEMM: 32x64 tile, BK=32, double-buffered ----------------
// C = act(Asplit @ Bsel + bias). A row-major (M,K) split at asplit into [A|A2].
// B row-major (K,N); column-block bn selects (B,bias,C,ldc) vs (B2,bias2,C2,ldc2)
// at column bsplit. OB16: store output as bf16 (ushort).
template<bool SILU, bool OB16>
__global__ __launch_bounds__(256) void k_gemm2(
    const float* __restrict__ A, int lda, const float* __restrict__ A2, int lda2, int asplit,
    const float* __restrict__ B, int ldb, const float* __restrict__ B2, int ldb2, int bsplit,
    const float* __restrict__ bias, const float* __restrict__ bias2,
    void* __restrict__ C, int ldc, void* __restrict__ C2, int ldc2,
    int M, int N, int K)
{
    __shared__ float As[2][32][34];
    __shared__ float Bs[2][32][64];
    int tid = threadIdx.x;
    int bm = blockIdx.y * 32;
    int bn = blockIdx.x * 64;

    const float* Bp; int ldb_; const float* biasp; void* Cp; int ldc_; int cb;
    if (bn < bsplit) { Bp = B;  ldb_ = ldb;  biasp = bias;  Cp = C;  ldc_ = ldc;  cb = bn; }
    else             { Bp = B2; ldb_ = ldb2; biasp = bias2; Cp = C2; ldc_ = ldc2; cb = bn - bsplit; }

    int arow  = tid >> 3;           // 0..31
    int akseg = (tid & 7) * 4;      // 0,4,...,28
    int bkr   = tid >> 4;           // 0..15
    int bcol  = (tid & 15) * 4;     // 0..60
    int tx = tid & 15, ty = tid >> 4;

    float4 aR, bR0, bR1;
    auto loadTile = [&](int k0) {
        int kl = k0 + akseg;
        const float* Ap; int ldA;
        if (kl < asplit) { Ap = A; ldA = lda; } else { Ap = A2; ldA = lda2; kl -= asplit; }
        aR  = *(const float4*)&Ap[(size_t)(bm + arow) * ldA + kl];
        bR0 = *(const float4*)&Bp[(size_t)(k0 + bkr)      * ldb_ + cb + bcol];
        bR1 = *(const float4*)&Bp[(size_t)(k0 + bkr + 16) * ldb_ + cb + bcol];
    };
    auto storeTile = [&](int c) {
        As[c][akseg+0][arow] = aR.x;
        As[c][akseg+1][arow] = aR.y;
        As[c][akseg+2][arow] = aR.z;
        As[c][akseg+3][arow] = aR.w;
        *(float4*)&Bs[c][bkr][bcol]      = bR0;
        *(float4*)&Bs[c][bkr + 16][bcol] = bR1;
    };

    float acc[2][4] = {{0.f,0.f,0.f,0.f},{0.f,0.f,0.f,0.f}};
    loadTile(0);
    storeTile(0);
    int steps = K >> 5;
    for (int s = 0; s < steps; s++) {
        int c = s & 1;
        __syncthreads();
        if (s + 1 < steps) loadTile((s + 1) << 5);
        #pragma unroll
        for (int kk = 0; kk < 32; kk++) {
            float2 a2v = *(const float2*)&As[c][kk][ty*2];
            float4 b4  = *(const float4*)&Bs[c][kk][tx*4];
            acc[0][0] += a2v.x*b4.x; acc[0][1] += a2v.x*b4.y;
            acc[0][2] += a2v.x*b4.z; acc[0][3] += a2v.x*b4.w;
            acc[1][0] += a2v.y*b4.x; acc[1][1] += a2v.y*b4.y;
            acc[1][2] += a2v.y*b4.z; acc[1][3] += a2v.y*b4.w;
        }
        if (s + 1 < steps) storeTile(1 - c);
    }
    #pragma unroll
    for (int i = 0; i < 2; i++) {
        int m = bm + ty*2 + i;
        float vals[4];
        #pragma unroll
        for (int j = 0; j < 4; j++) {
            float val = acc[i][j] + (biasp ? biasp[cb + tx*4 + j] : 0.0f);
            if (SILU) val = val / (1.0f + __expf(-val));
            vals[j] = val;
        }
        if constexpr (OB16) {
            ushort4 o;
            o.x = f2bf(vals[0]); o.y = f2bf(vals[1]); o.z = f2bf(vals[2]); o.w = f2bf(vals[3]);
            *(ushort4*)&((ushort*)Cp)[(size_t)m * ldc_ + cb + tx*4] = o;
        } else {
            float4 o;
            o.x = vals[0]; o.y = vals[1]; o.z = vals[2]; o.w = vals[3];
            *(float4*)&((float*)Cp)[(size_t)m * ldc_ + cb + tx*4] = o;
        }
    }
}

// ---------------- edge aggregation v3 ----------------
// 192 threads = 3 waves; wave g owns message section g (128 channels as 64 bf16 pairs).
// PHI and v gathered as packed bf16x2; RBF/UNITFC pre-staged in LDS per 64-edge batch.
__global__ __launch_bounds__(192) void k_aggregate(
    const ushort* __restrict__ PHIB, const ushort* __restrict__ VBF,
    const float* __restrict__ vin, float* __restrict__ S, float* __restrict__ vout,
    const float* __restrict__ RBF, const float* __restrict__ UNITFC,
    const int* __restrict__ esrc, const int* __restrict__ OFF, const int* __restrict__ EIDX,
    const float* __restrict__ rbfw, const float* __restrict__ rbfb)
{
    int a = blockIdx.x;
    int tid = threadIdx.x;
    int g = tid >> 6;          // wave: 0=ds, 1=v*dvv, 2=unit*dvs
    int p = tid & 63;
    int c0 = 2 * p;            // channel pair within section

    float w0[RDIM], w1[RDIM];
    const float* wc = rbfw + g*128 + c0;
    #pragma unroll
    for (int r = 0; r < RDIM; r++) { w0[r] = wc[r*384]; w1[r] = wc[r*384 + 1]; }
    float bb0 = rbfb[g*128 + c0], bb1 = rbfb[g*128 + c0 + 1];

    __shared__ int sE[64], sSrc[64];
    __shared__ float4 sRBF[64][5];
    __shared__ float4 sUFC[64];
    __shared__ float avs[3][128];

    int beg = OFF[a], end = OFF[a + 1];
    float d00 = 0.f, d01 = 0.f;                       // g==0
    float a00=0.f,a01=0.f,a10=0.f,a11=0.f,a20=0.f,a21=0.f;  // g==1 / g==2

    for (int p0 = beg; p0 < end; p0 += 64) {
        int n = end - p0; if (n > 64) n = 64;
        if (tid < n) { int e = EIDX[p0 + tid]; sE[tid] = e; sSrc[tid] = esrc[e]; }
        __syncthreads();
        for (int i = tid; i < n*5; i += 192) {
            int q = i / 5, r = i - q*5;
            sRBF[q][r] = ((const float4*)(RBF + (size_t)sE[q] * RDIM))[r];
        }
        for (int i = tid; i < n; i += 192)
            sUFC[i] = *(const float4*)(UNITFC + (size_t)sE[i] * 4);
        __syncthreads();
        for (int q = 0; q < n; q++) {
            int src = sSrc[q];
            float4 r0 = sRBF[q][0], r1 = sRBF[q][1], r2 = sRBF[q][2],
                   r3 = sRBF[q][3], r4 = sRBF[q][4];
            float4 ufc = sUFC[q];
            uint up = *(const uint*)&PHIB[(size_t)src*384 + g*128 + c0];
            float ph0 = __uint_as_float(up << 16);
            float ph1 = __uint_as_float(up & 0xffff0000u);
            float f0 = bb0, f1 = bb1;
            f0 += r0.x*w0[0]  + r0.y*w0[1]  + r0.z*w0[2]  + r0.w*w0[3];
            f1 += r0.x*w1[0]  + r0.y*w1[1]  + r0.z*w1[2]  + r0.w*w1[3];
            f0 += r1.x*w0[4]  + r1.y*w0[5]  + r1.z*w0[6]  + r1.w*w0[7];
            f1 += r1.x*w1[4]  + r1.y*w1[5]  + r1.z*w1[6]  + r1.w*w1[7];
            f0 += r2.x*w0[8]  + r2.y*w0[9]  + r2.z*w0[10] + r2.w*w0[11];
            f1 += r2.x*w1[8]  + r2.y*w1[9]  + r2.z*w1[10] + r2.w*w1[11];
            f0 += r3.x*w0[12] + r3.y*w0[13] + r3.z*w0[14] + r3.w*w0[15];
            f1 += r3.x*w1[12] + r3.y*w1[13] + r3.z*w1[14] + r3.w*w1[15];
            f0 += r4.x*w0[16] + r4.y*w0[17] + r4.z*w0[18] + r4.w*w0[19];
            f1 += r4.x*w1[16] + r4.y*w1[17] + r4.z*w1[18] + r4.w*w1[19];
            float m0 = ph0 * (f0 * ufc.w);
            float m1 = ph1 * (f1 * ufc.w);
            if (g == 0) {
                d00 += m0; d01 += m1;
            } else if (g == 1) {
                size_t vb = (size_t)src * 384 + c0;
                uint v0p = *(const uint*)&VBF[vb];
                uint v1p = *(const uint*)&VBF[vb + 128];
                uint v2p = *(const uint*)&VBF[vb + 256];
                a00 += __uint_as_float(v0p << 16) * m0;
                a01 += __uint_as_float(v0p & 0xffff0000u) * m1;
                a10 += __uint_as_float(v1p << 16) * m0;
                a11 += __uint_as_float(v1p & 0xffff0000u) * m1;
                a20 += __uint_as_float(v2p << 16) * m0;
                a21 += __uint_as_float(v2p & 0xffff0000u) * m1;
            } else {
                a00 += ufc.x * m0; a01 += ufc.x * m1;
                a10 += ufc.y * m0; a11 += ufc.y * m1;
                a20 += ufc.z * m0; a21 += ufc.z * m1;
            }
        }
        __syncthreads();
    }

    if (g == 1) {
        avs[0][c0] = a00; avs[0][c0+1] = a01;
        avs[1][c0] = a10; avs[1][c0+1] = a11;
        avs[2][c0] = a20; avs[2][c0+1] = a21;
    }
    __syncthreads();
    if (g == 0) {
        float2 s2 = *(float2*)&S[(size_t)a*128 + c0];
        s2.x += d00; s2.y += d01;
        *(float2*)&S[(size_t)a*128 + c0] = s2;
    } else if (g == 2) {
        float own0[3] = {a00, a10, a20};
        float own1[3] = {a01, a11, a21};
        #pragma unroll
        for (int c = 0; c < 3; c++) {
            size_t vb = (size_t)a*384 + c*128 + c0;
            float2 vi = *(const float2*)&vin[vb];
            vi.x += avs[c][c0]     + own0[c];
            vi.y += avs[c][c0 + 1] + own1[c];
            *(float2*)&vout[vb] = vi;
        }
    }
}

// ---------------- vv-norm + <uv,vv> ----------------
__global__ void k_vvdot(const float* __restrict__ UV, const float* __restrict__ VV,
                        float* __restrict__ VVN, float* __restrict__ DOT) {
    int i = blockIdx.x * 256 + threadIdx.x;           // over 8192*128
    int a = i >> 7, k = i & 127;
    size_t b = (size_t)a * 384 + k;
    float u0 = UV[b], u1 = UV[b+128], u2 = UV[b+256];
    float v0 = VV[b], v1 = VV[b+128], v2 = VV[b+256];
    VVN[i] = sqrtf(v0*v0 + v1*v1 + v2*v2 + EPSV);
    DOT[i] = u0*v0 + u1*v1 + u2*v2;
}

// ---------------- s,v update epilogue (+ bf16 shadow of v) ----------------
__global__ void k_update(float* __restrict__ S, float* __restrict__ v,
                         ushort* __restrict__ VBF,
                         const float* __restrict__ Abuf, const float* __restrict__ UV,
                         const float* __restrict__ DOT) {
    int i = blockIdx.x * 256 + threadIdx.x;           // over 8192*128
    int a = i >> 7, k = i & 127;
    size_t b = (size_t)a * 384 + k;
    float a_vv = Abuf[b], a_sv = Abuf[b+128], a_ss = Abuf[b+256];
    S[i] += a_ss + a_sv * DOT[i];
    float n0 = v[b]       + a_vv * UV[b];
    float n1 = v[b + 128] + a_vv * UV[b + 128];
    float n2 = v[b + 256] + a_vv * UV[b + 256];
    v[b] = n0; v[b + 128] = n1; v[b + 256] = n2;
    VBF[b] = f2bf(n0); VBF[b + 128] = f2bf(n1); VBF[b + 256] = f2bf(n2);
}

// ---------------- readout dot: AOUT[a] = H[a,:] . w2 + b2 ----------------
__global__ __launch_bounds__(256) void k_dot(const float* __restrict__ H,
                                             const float* __restrict__ w2,
                                             const float* __restrict__ b2v,
                                             float* __restrict__ AOUT) {
    int lane = threadIdx.x & 63;
    int wv = threadIdx.x >> 6;
    int a = blockIdx.x * 4 + wv;
    const float* h = &H[(size_t)a * 128];
    float p = h[lane] * w2[lane] + h[64 + lane] * w2[64 + lane];
    #pragma unroll
    for (int off = 32; off > 0; off >>= 1) p += __shfl_down(p, off);
    if (lane == 0) AOUT[a] = p + b2v[0];
}

// ---------------- per-molecule sum (parallel) ----------------
__global__ void k_molsum(const float* __restrict__ AOUT, const int* __restrict__ mol,
                         float* __restrict__ out) {
    __shared__ float acc[N_MOL];
    int t = threadIdx.x;
    if (t < N_MOL) acc[t] = 0.f;
    __syncthreads();
    for (int i = blockIdx.x * 256 + t; i < N_ATOMS; i += 256 * 32)
        atomicAdd(&acc[mol[i]], AOUT[i]);
    __syncthreads();
    if (t < N_MOL) atomicAdd(&out[t], acc[t]);
}

extern "C" void kernel_launch(void* const* d_in, const int* in_sizes, int n_in,
                              void* d_out, int out_size, void* d_ws, size_t ws_size,
                              hipStream_t stream) {
    const int*   z      = (const int*)d_in[0];
    const float* pos    = (const float*)d_in[1];
    const int*   esrc   = (const int*)d_in[2];
    const int*   edst   = (const int*)d_in[3];
    const int*   mol    = (const int*)d_in[4];
    const float* embed  = (const float*)d_in[5];
    const float* msg_w1 = (const float*)d_in[6];
    const float* msg_b1 = (const float*)d_in[7];
    const float* msg_w2 = (const float*)d_in[8];
    const float* msg_b2 = (const float*)d_in[9];
    const float* rbf_w  = (const float*)d_in[10];
    const float* rbf_b  = (const float*)d_in[11];
    const float* upd_u  = (const float*)d_in[12];
    const float* upd_v  = (const float*)d_in[13];
    const float* upd_a1 = (const float*)d_in[14];
    const float* upd_a1b= (const float*)d_in[15];
    const float* upd_a2 = (const float*)d_in[16];
    const float* upd_a2b= (const float*)d_in[17];
    const float* out_w1 = (const float*)d_in[18];
    const float* out_b1 = (const float*)d_in[19];
    const float* out_w2 = (const float*)d_in[20];
    const float* out_b2 = (const float*)d_in[21];

    float* ws = (float*)d_ws;
    float* S      = ws; ws += 1048576;     // 8192*128
    float* Va     = ws; ws += 3145728;     // 8192*3*128
    float* Vb     = ws; ws += 3145728;
    float* ABUF   = ws; ws += 3145728;     // a-output f32; aliased as VV
    float* RBF    = ws; ws += 5242880;     // 262144*20
    float* UNITFC = ws; ws += 1048576;     // 262144*4 (ux,uy,uz,fc)
    float* UV     = ws; ws += 3145728;
    float* VVN    = ws; ws += 1048576;
    float* DOT    = ws; ws += 1048576;
    float* H      = ws; ws += 1048576;
    float* AOUT   = ws; ws += 8192;
    ushort* PHIB  = (ushort*)ws; ws += 1572864;   // 8192*384 bf16
    ushort* VBF   = (ushort*)ws; ws += 1572864;   // 8192*384 bf16 shadow of v
    int* CNT  = (int*)ws;
    int* OFF  = CNT + 8192;
    int* CUR  = OFF + 8193;
    int* EIDX = CUR + 8192;
    float* VV = ABUF;   // lifetime-disjoint alias

    hipMemsetAsync(Va, 0, 3145728 * sizeof(float), stream);
    hipMemsetAsync(VBF, 0, 3145728 * sizeof(ushort), stream);
    hipMemsetAsync(CNT, 0, 8192 * sizeof(int), stream);

    k_embed<<<4096, 256, 0, stream>>>(z, embed, S);
    k_edges<<<1024, 256, 0, stream>>>(pos, esrc, edst, RBF, UNITFC);
    k_hist<<<1024, 256, 0, stream>>>(edst, CNT);
    k_scan<<<1, 1024, 0, stream>>>(CNT, OFF, CUR);
    k_fill<<<1024, 256, 0, stream>>>(edst, CUR, EIDX);

    for (int l = 0; l < LLAYERS; l++) {
        const float* vin_ = (l & 1) ? Vb : Va;
        float*       vout_= (l & 1) ? Va : Vb;
        const float* mw1 = msg_w1 + (size_t)l*128*128;
        const float* mw2 = msg_w2 + (size_t)l*128*384;
        const float* uu  = upd_u  + (size_t)l*128*128;
        const float* uv_ = upd_v  + (size_t)l*128*128;
        const float* a1  = upd_a1 + (size_t)l*256*128;
        const float* a2  = upd_a2 + (size_t)l*128*384;

        // H = silu(S@w1+b1)
        k_gemm2<true, false><<<dim3(2, 256), 256, 0, stream>>>(
            S, 128, nullptr, 0, 128, mw1, 128, nullptr, 0, 128,
            msg_b1 + (size_t)l*128, nullptr, H, 128, nullptr, 0, 8192, 128, 128);
        // PHIB(bf16) = H@w2+b2
        k_gemm2<false, true><<<dim3(6, 256), 256, 0, stream>>>(
            H, 128, nullptr, 0, 128, mw2, 384, nullptr, 0, 384,
            msg_b2 + (size_t)l*384, nullptr, PHIB, 384, nullptr, 0, 8192, 384, 128);
        // message aggregation
        k_aggregate<<<8192, 192, 0, stream>>>(PHIB, VBF, vin_, S, vout_, RBF, UNITFC,
            esrc, OFF, EIDX, rbf_w + (size_t)l*20*384, rbf_b + (size_t)l*384);
        // UV | VV in one call (B/C column split at 128)
        k_gemm2<false, false><<<dim3(4, 768), 256, 0, stream>>>(
            vout_, 128, nullptr, 0, 128, uu, 128, uv_, 128, 128,
            nullptr, nullptr, UV, 128, VV, 128, 24576, 256, 128);
        k_vvdot<<<4096, 256, 0, stream>>>(UV, VV, VVN, DOT);
        // H = silu([S|VVN]@a1+b1)   (A split at K=128)
        k_gemm2<true, false><<<dim3(2, 256), 256, 0, stream>>>(
            S, 128, VVN, 128, 128, a1, 128, nullptr, 0, 128,
            upd_a1b + (size_t)l*128, nullptr, H, 128, nullptr, 0, 8192, 128, 256);
        // a-out = H@a2+b2 (f32, into ABUF)
        k_gemm2<false, false><<<dim3(6, 256), 256, 0, stream>>>(
            H, 128, nullptr, 0, 128, a2, 384, nullptr, 0, 384,
            upd_a2b + (size_t)l*384, nullptr, ABUF, 384, nullptr, 0, 8192, 384, 128);
        k_update<<<4096, 256, 0, stream>>>(S, vout_, VBF, ABUF, UV, DOT);
    }

    // readout: H = silu(S@out_w1+b1); AOUT = H.w2+b2; molecule sum
    k_gemm2<true, false><<<dim3(2, 256), 256, 0, stream>>>(
        S, 128, nullptr, 0, 128, out_w1, 128, nullptr, 0, 128,
        out_b1, nullptr, H, 128, nullptr, 0, 8192, 128, 128);
    k_dot<<<2048, 256, 0, stream>>>(H, out_w2, out_b2, AOUT);
    hipMemsetAsync(d_out, 0, N_MOL * sizeof(float), stream);
    k_molsum<<<32, 256, 0, stream>>>(AOUT, mol, (float*)d_out);
}

// Round 6
// 908.238 us; speedup vs baseline: 1.2914x; 1.2180x over previous
//
#include <hip/hip_runtime.h>
#include <hip/hip_bf16.h>
#include <math.h>

#define N_ATOMS 8192
#define N_EDGES 262144
#define N_MOL   128
#define FDIM    128
#define RDIM    20
#define LLAYERS 3
#define CUTOFF  5.0f
#define EPSV    1e-8f
#define PI_F    3.14159265358979323846f

typedef __attribute__((ext_vector_type(8))) short bf16x8;
typedef __attribute__((ext_vector_type(4))) float f32x4;

__device__ __forceinline__ ushort f2bf(float x) {
    uint b = __float_as_uint(x);
    return (ushort)((b + 0x7fffu + ((b >> 16) & 1u)) >> 16);
}

// ---------------- weight convert+transpose (f32 KxN -> bf16 NxK), all at once ----------------
// WT layout: W1T[3]@0 (128x128) | W2T[3]@49152 (384x128) | UVT[3]@196608 (256x128)
//            A1T[3]@294912 (128x256) | A2T[3]@393216 (384x128) | OW1T@540672 (128x128)
__global__ void k_wconv(const float* __restrict__ w1, const float* __restrict__ w2,
                        const float* __restrict__ uu, const float* __restrict__ uvw,
                        const float* __restrict__ a1, const float* __restrict__ a2,
                        const float* __restrict__ ow1, ushort* __restrict__ WT) {
    int i = blockIdx.x * 256 + threadIdx.x;  // < 557056
    float v;
    if (i < 49152) {                          // W1T
        int idx = i; int l = idx >> 14; idx &= 16383;
        int n = idx >> 7, k = idx & 127;
        v = w1[l*16384 + k*128 + n];
    } else if (i < 196608) {                  // W2T
        int idx = i - 49152; int l = idx / 49152; idx -= l * 49152;
        int n = idx >> 7, k = idx & 127;
        v = w2[l*49152 + k*384 + n];
    } else if (i < 294912) {                  // UVT (u cols 0-127, v cols 128-255)
        int idx = i - 196608; int l = idx >> 15; idx &= 32767;
        int n = idx >> 7, k = idx & 127;
        v = (n < 128) ? uu[l*16384 + k*128 + n] : uvw[l*16384 + k*128 + (n-128)];
    } else if (i < 393216) {                  // A1T (K=256)
        int idx = i - 294912; int l = idx >> 15; idx &= 32767;
        int n = idx >> 8, k = idx & 255;
        v = a1[l*32768 + k*128 + n];
    } else if (i < 540672) {                  // A2T
        int idx = i - 393216; int l = idx / 49152; idx -= l * 49152;
        int n = idx >> 7, k = idx & 127;
        v = a2[l*49152 + k*384 + n];
    } else {                                  // OW1T
        int idx = i - 540672;
        int n = idx >> 7, k = idx & 127;
        v = ow1[k*128 + n];
    }
    WT[i] = f2bf(v);
}

// ---------------- embed gather ----------------
__global__ void k_embed(const int* __restrict__ z, const float* __restrict__ embed,
                        float* __restrict__ S, ushort* __restrict__ SBF) {
    int i = blockIdx.x * 256 + threadIdx.x;
    int a = i >> 7, k = i & 127;
    float v = embed[(size_t)z[a] * FDIM + k];
    S[i] = v; SBF[i] = f2bf(v);
}

// ---------------- CSR build ----------------
__global__ void k_hist(const int* __restrict__ edst, int* __restrict__ CNT) {
    int e = blockIdx.x * 256 + threadIdx.x;
    if (e < N_EDGES) atomicAdd(&CNT[edst[e]], 1);
}

__global__ __launch_bounds__(1024) void k_scan(const int* __restrict__ CNT,
                                               int* __restrict__ OFF, int* __restrict__ CUR) {
    __shared__ int part[1024];
    int t = threadIdx.x;
    int loc[8];
    int run = 0;
    #pragma unroll
    for (int i = 0; i < 8; i++) { int c = CNT[t*8 + i]; loc[i] = run; run += c; }
    part[t] = run;
    __syncthreads();
    for (int off = 1; off < 1024; off <<= 1) {
        int v = 0;
        if (t >= off) v = part[t - off];
        __syncthreads();
        part[t] += v;
        __syncthreads();
    }
    int ebase = (t > 0) ? part[t-1] : 0;
    #pragma unroll
    for (int i = 0; i < 8; i++) { int o = ebase + loc[i]; OFF[t*8+i] = o; CUR[t*8+i] = o; }
    if (t == 1023) OFF[8192] = part[1023];
}

__global__ void k_pos(const int* __restrict__ edst, int* __restrict__ CUR,
                      int* __restrict__ POS) {
    int e = blockIdx.x * 256 + threadIdx.x;
    if (e < N_EDGES) POS[e] = atomicAdd(&CUR[edst[e]], 1);
}

// ---------------- edge geometry + rbf, written in CSR-sorted order ----------------
__global__ void k_edges(const float* __restrict__ pos, const int* __restrict__ esrc,
                        const int* __restrict__ edst, const int* __restrict__ POS,
                        float* __restrict__ RBF, float* __restrict__ UNITFC,
                        int* __restrict__ SRCS) {
    int e = blockIdx.x * 256 + threadIdx.x;
    if (e >= N_EDGES) return;
    int s = esrc[e], d = edst[e];
    int p = POS[e];
    float rx = pos[d*3+0] - pos[s*3+0];
    float ry = pos[d*3+1] - pos[s*3+1];
    float rz = pos[d*3+2] - pos[s*3+2];
    float dd = sqrtf(rx*rx + ry*ry + rz*rz + EPSV);
    float inv = 1.0f / dd;
    float fc = (dd < CUTOFF) ? 0.5f * (cosf(dd * (PI_F / CUTOFF)) + 1.0f) : 0.0f;
    float4 u4; u4.x = rx*inv; u4.y = ry*inv; u4.z = rz*inv; u4.w = fc;
    *(float4*)&UNITFC[(size_t)p*4] = u4;
    SRCS[p] = s;
    float rb[RDIM];
    #pragma unroll
    for (int r = 0; r < RDIM; r++) {
        float freq = (float)(r + 1) * (PI_F / CUTOFF);
        rb[r] = sinf(dd * freq) * inv;
    }
    float4* out = (float4*)&RBF[(size_t)p * RDIM];
    #pragma unroll
    for (int q = 0; q < 5; q++) {
        float4 o; o.x = rb[q*4]; o.y = rb[q*4+1]; o.z = rb[q*4+2]; o.w = rb[q*4+3];
        out[q] = o;
    }
}

// ---------------- bf16 MFMA GEMM ----------------
// C = act(A @ BT^T + bias); A bf16 (M,K) row-major split at asplit; BT bf16 (N,K) row-major.
// Block 128 thr = 2 waves; tile 32(M) x 64(N); wave w owns rows w*16..+16.
template<bool SILU, bool WF32, bool WB16, bool CSPLIT>
__global__ __launch_bounds__(128) void k_mgemm(
    const ushort* __restrict__ A, int lda, const ushort* __restrict__ A2, int lda2, int asplit,
    const ushort* __restrict__ BT, int ldbt, const float* __restrict__ bias,
    float* __restrict__ C, int ldc, float* __restrict__ C2, int ldc2, int csplit,
    ushort* __restrict__ CB, int ldcb, int K)
{
    int tid = threadIdx.x;
    int w = tid >> 6, l = tid & 63;
    int bm = blockIdx.y * 32 + w * 16;
    int bn = blockIdx.x * 64;
    int lrow = l & 15, lk = (l >> 4) * 8;

    f32x4 acc[4] = {{0.f,0.f,0.f,0.f},{0.f,0.f,0.f,0.f},{0.f,0.f,0.f,0.f},{0.f,0.f,0.f,0.f}};
    for (int k0 = 0; k0 < K; k0 += 32) {
        int ka = k0 + lk;
        const ushort* Ap; int ldA;
        if (ka < asplit) { Ap = A; ldA = lda; } else { Ap = A2; ldA = lda2; ka -= asplit; }
        bf16x8 af = *(const bf16x8*)&Ap[(size_t)(bm + lrow) * ldA + ka];
        #pragma unroll
        for (int t = 0; t < 4; t++) {
            bf16x8 bfr = *(const bf16x8*)&BT[(size_t)(bn + t*16 + lrow) * ldbt + k0 + lk];
            acc[t] = __builtin_amdgcn_mfma_f32_16x16x32_bf16(af, bfr, acc[t], 0, 0, 0);
        }
    }
    #pragma unroll
    for (int t = 0; t < 4; t++) {
        int col = bn + t*16 + lrow;
        float bv = bias ? bias[col] : 0.0f;
        #pragma unroll
        for (int j = 0; j < 4; j++) {
            int row = bm + (l >> 4) * 4 + j;
            float val = acc[t][j] + bv;
            if (SILU) val = val / (1.0f + __expf(-val));
            if (WF32) {
                if (CSPLIT && col >= csplit) C2[(size_t)row * ldc2 + (col - csplit)] = val;
                else                         C [(size_t)row * ldc  + col] = val;
            }
            if (WB16) CB[(size_t)row * ldcb + col] = f2bf(val);
        }
    }
}

// ---------------- edge aggregation v4: CSR-sorted streams ----------------
__global__ __launch_bounds__(192) void k_aggregate(
    const ushort* __restrict__ PHIB, const ushort* __restrict__ VBFA,
    float* __restrict__ S, ushort* __restrict__ SBF,
    float* __restrict__ V, ushort* __restrict__ VBFB,
    const float* __restrict__ RBF, const float* __restrict__ UNITFC,
    const int* __restrict__ SRCS, const int* __restrict__ OFF,
    const float* __restrict__ rbfw, const float* __restrict__ rbfb)
{
    int a = blockIdx.x;
    int tid = threadIdx.x;
    int g = tid >> 6;          // wave role: 0=ds, 1=v*dvv, 2=unit*dvs
    int c0 = 2 * (tid & 63);   // channel pair within section

    float w0[RDIM], w1[RDIM];
    const float* wc = rbfw + g*128 + c0;
    #pragma unroll
    for (int r = 0; r < RDIM; r++) { w0[r] = wc[r*384]; w1[r] = wc[r*384 + 1]; }
    float bb0 = rbfb[g*128 + c0], bb1 = rbfb[g*128 + c0 + 1];

    __shared__ int sSrc[64];
    __shared__ float4 sRBF[320];
    __shared__ float4 sUFC[64];
    __shared__ float avs[3][128];

    int beg = OFF[a], end = OFF[a + 1];
    float d00 = 0.f, d01 = 0.f;
    float a00=0.f,a01=0.f,a10=0.f,a11=0.f,a20=0.f,a21=0.f;

    for (int p0 = beg; p0 < end; p0 += 64) {
        int n = end - p0; if (n > 64) n = 64;
        __syncthreads();
        if (tid < n) sSrc[tid] = SRCS[p0 + tid];
        for (int i = tid; i < n; i += 192)
            sUFC[i] = *(const float4*)(UNITFC + (size_t)(p0 + i) * 4);
        const float4* rsrc = (const float4*)(RBF + (size_t)p0 * RDIM);
        for (int i = tid; i < n*5; i += 192) sRBF[i] = rsrc[i];
        __syncthreads();
        for (int q = 0; q < n; q++) {
            int src = sSrc[q];
            float4 r0 = sRBF[q*5+0], r1 = sRBF[q*5+1], r2 = sRBF[q*5+2],
                   r3 = sRBF[q*5+3], r4 = sRBF[q*5+4];
            float4 ufc = sUFC[q];
            uint up = *(const uint*)&PHIB[(size_t)src*384 + g*128 + c0];
            float ph0 = __uint_as_float(up << 16);
            float ph1 = __uint_as_float(up & 0xffff0000u);
            float f0 = bb0, f1 = bb1;
            f0 += r0.x*w0[0]  + r0.y*w0[1]  + r0.z*w0[2]  + r0.w*w0[3];
            f1 += r0.x*w1[0]  + r0.y*w1[1]  + r0.z*w1[2]  + r0.w*w1[3];
            f0 += r1.x*w0[4]  + r1.y*w0[5]  + r1.z*w0[6]  + r1.w*w0[7];
            f1 += r1.x*w1[4]  + r1.y*w1[5]  + r1.z*w1[6]  + r1.w*w1[7];
            f0 += r2.x*w0[8]  + r2.y*w0[9]  + r2.z*w0[10] + r2.w*w0[11];
            f1 += r2.x*w1[8]  + r2.y*w1[9]  + r2.z*w1[10] + r2.w*w1[11];
            f0 += r3.x*w0[12] + r3.y*w0[13] + r3.z*w0[14] + r3.w*w0[15];
            f1 += r3.x*w1[12] + r3.y*w1[13] + r3.z*w1[14] + r3.w*w1[15];
            f0 += r4.x*w0[16] + r4.y*w0[17] + r4.z*w0[18] + r4.w*w0[19];
            f1 += r4.x*w1[16] + r4.y*w1[17] + r4.z*w1[18] + r4.w*w1[19];
            float m0 = ph0 * (f0 * ufc.w);
            float m1 = ph1 * (f1 * ufc.w);
            if (g == 0) {
                d00 += m0; d01 += m1;
            } else if (g == 1) {
                size_t vb = (size_t)src * 384 + c0;
                uint v0p = *(const uint*)&VBFA[vb];
                uint v1p = *(const uint*)&VBFA[vb + 128];
                uint v2p = *(const uint*)&VBFA[vb + 256];
                a00 += __uint_as_float(v0p << 16) * m0;
                a01 += __uint_as_float(v0p & 0xffff0000u) * m1;
                a10 += __uint_as_float(v1p << 16) * m0;
                a11 += __uint_as_float(v1p & 0xffff0000u) * m1;
                a20 += __uint_as_float(v2p << 16) * m0;
                a21 += __uint_as_float(v2p & 0xffff0000u) * m1;
            } else {
                a00 += ufc.x * m0; a01 += ufc.x * m1;
                a10 += ufc.y * m0; a11 += ufc.y * m1;
                a20 += ufc.z * m0; a21 += ufc.z * m1;
            }
        }
    }

    if (g == 1) {
        avs[0][c0] = a00; avs[0][c0+1] = a01;
        avs[1][c0] = a10; avs[1][c0+1] = a11;
        avs[2][c0] = a20; avs[2][c0+1] = a21;
    }
    __syncthreads();
    if (g == 0) {
        size_t sb = (size_t)a*128 + c0;
        float2 s2 = *(float2*)&S[sb];
        s2.x += d00; s2.y += d01;
        *(float2*)&S[sb] = s2;
        SBF[sb] = f2bf(s2.x); SBF[sb+1] = f2bf(s2.y);
    } else if (g == 2) {
        float own0[3] = {a00, a10, a20};
        float own1[3] = {a01, a11, a21};
        #pragma unroll
        for (int c = 0; c < 3; c++) {
            size_t vb = (size_t)a*384 + c*128 + c0;
            float2 vi = *(const float2*)&V[vb];
            vi.x += avs[c][c0]     + own0[c];
            vi.y += avs[c][c0 + 1] + own1[c];
            *(float2*)&V[vb] = vi;
            VBFB[vb] = f2bf(vi.x); VBFB[vb+1] = f2bf(vi.y);
        }
    }
}

// ---------------- vv-norm + <uv,vv> ----------------
__global__ void k_vvdot(const float* __restrict__ UV, const float* __restrict__ VV,
                        ushort* __restrict__ VVNB, float* __restrict__ DOT) {
    int i = blockIdx.x * 256 + threadIdx.x;
    int a = i >> 7, k = i & 127;
    size_t b = (size_t)a * 384 + k;
    float u0 = UV[b], u1 = UV[b+128], u2 = UV[b+256];
    float v0 = VV[b], v1 = VV[b+128], v2 = VV[b+256];
    VVNB[i] = f2bf(sqrtf(v0*v0 + v1*v1 + v2*v2 + EPSV));
    DOT[i] = u0*v0 + u1*v1 + u2*v2;
}

// ---------------- s,v update epilogue (+ bf16 shadows) ----------------
__global__ void k_update(float* __restrict__ S, ushort* __restrict__ SBF,
                         float* __restrict__ V, ushort* __restrict__ VBFA,
                         const float* __restrict__ Abuf, const float* __restrict__ UV,
                         const float* __restrict__ DOT) {
    int i = blockIdx.x * 256 + threadIdx.x;
    int a = i >> 7, k = i & 127;
    size_t b = (size_t)a * 384 + k;
    float a_vv = Abuf[b], a_sv = Abuf[b+128], a_ss = Abuf[b+256];
    float sn = S[i] + a_ss + a_sv * DOT[i];
    S[i] = sn; SBF[i] = f2bf(sn);
    float n0 = V[b]       + a_vv * UV[b];
    float n1 = V[b + 128] + a_vv * UV[b + 128];
    float n2 = V[b + 256] + a_vv * UV[b + 256];
    V[b] = n0; V[b + 128] = n1; V[b + 256] = n2;
    VBFA[b] = f2bf(n0); VBFA[b + 128] = f2bf(n1); VBFA[b + 256] = f2bf(n2);
}

// ---------------- readout dot ----------------
__global__ __launch_bounds__(256) void k_dot(const float* __restrict__ H,
                                             const float* __restrict__ w2,
                                             const float* __restrict__ b2v,
                                             float* __restrict__ AOUT) {
    int lane = threadIdx.x & 63;
    int wv = threadIdx.x >> 6;
    int a = blockIdx.x * 4 + wv;
    const float* h = &H[(size_t)a * 128];
    float p = h[lane] * w2[lane] + h[64 + lane] * w2[64 + lane];
    #pragma unroll
    for (int off = 32; off > 0; off >>= 1) p += __shfl_down(p, off);
    if (lane == 0) AOUT[a] = p + b2v[0];
}

// ---------------- per-molecule sum ----------------
__global__ void k_molsum(const float* __restrict__ AOUT, const int* __restrict__ mol,
                         float* __restrict__ out) {
    __shared__ float acc[N_MOL];
    int t = threadIdx.x;
    if (t < N_MOL) acc[t] = 0.f;
    __syncthreads();
    for (int i = blockIdx.x * 256 + t; i < N_ATOMS; i += 256 * 32)
        atomicAdd(&acc[mol[i]], AOUT[i]);
    __syncthreads();
    if (t < N_MOL) atomicAdd(&out[t], acc[t]);
}

extern "C" void kernel_launch(void* const* d_in, const int* in_sizes, int n_in,
                              void* d_out, int out_size, void* d_ws, size_t ws_size,
                              hipStream_t stream) {
    const int*   z      = (const int*)d_in[0];
    const float* pos    = (const float*)d_in[1];
    const int*   esrc   = (const int*)d_in[2];
    const int*   edst   = (const int*)d_in[3];
    const int*   mol    = (const int*)d_in[4];
    const float* embed  = (const float*)d_in[5];
    const float* msg_w1 = (const float*)d_in[6];
    const float* msg_b1 = (const float*)d_in[7];
    const float* msg_w2 = (const float*)d_in[8];
    const float* msg_b2 = (const float*)d_in[9];
    const float* rbf_w  = (const float*)d_in[10];
    const float* rbf_b  = (const float*)d_in[11];
    const float* upd_u  = (const float*)d_in[12];
    const float* upd_v  = (const float*)d_in[13];
    const float* upd_a1 = (const float*)d_in[14];
    const float* upd_a1b= (const float*)d_in[15];
    const float* upd_a2 = (const float*)d_in[16];
    const float* upd_a2b= (const float*)d_in[17];
    const float* out_w1 = (const float*)d_in[18];
    const float* out_b1 = (const float*)d_in[19];
    const float* out_w2 = (const float*)d_in[20];
    const float* out_b2 = (const float*)d_in[21];

    float* ws = (float*)d_ws;
    float* S      = ws; ws += 1048576;     // 8192*128 f32
    float* V      = ws; ws += 3145728;     // 8192*3*128 f32 (in-place across layers)
    float* ABUF   = ws; ws += 3145728;     // a2-out f32; alias VV and readout-H
    float* UV     = ws; ws += 3145728;
    float* DOT    = ws; ws += 1048576;
    float* RBF    = ws; ws += 5242880;     // sorted, 262144*20
    float* UNITFC = ws; ws += 1048576;     // sorted, 262144*4
    float* AOUT   = ws; ws += 8192;
    ushort* PHIB  = (ushort*)ws; ws += 1572864;   // 8192*384
    ushort* VBFA  = (ushort*)ws; ws += 1572864;   // v bf16 (gather table)
    ushort* VBFB  = (ushort*)ws; ws += 1572864;   // vout bf16 (GEMM A)
    ushort* SBF   = (ushort*)ws; ws += 524288;    // 8192*128
    ushort* VVNB  = (ushort*)ws; ws += 524288;
    ushort* HB    = (ushort*)ws; ws += 524288;
    ushort* H2B   = (ushort*)ws; ws += 524288;
    ushort* WT    = (ushort*)ws; ws += 278528;    // 557056 bf16 weights
    int* CNT  = (int*)ws;
    int* OFF  = CNT + 8192;
    int* CUR  = OFF + 8193;
    int* POS  = CUR + 8192;
    int* SRCS = POS + N_EDGES;
    float* VV = ABUF;                  // lifetime-disjoint aliases
    float* H  = ABUF;

    hipMemsetAsync(V, 0, 3145728 * sizeof(float), stream);
    hipMemsetAsync(VBFA, 0, 3145728 * sizeof(ushort), stream);
    hipMemsetAsync(CNT, 0, 8192 * sizeof(int), stream);

    k_wconv<<<2176, 256, 0, stream>>>(msg_w1, msg_w2, upd_u, upd_v, upd_a1, upd_a2, out_w1, WT);
    k_embed<<<4096, 256, 0, stream>>>(z, embed, S, SBF);
    k_hist<<<1024, 256, 0, stream>>>(edst, CNT);
    k_scan<<<1, 1024, 0, stream>>>(CNT, OFF, CUR);
    k_pos<<<1024, 256, 0, stream>>>(edst, CUR, POS);
    k_edges<<<1024, 256, 0, stream>>>(pos, esrc, edst, POS, RBF, UNITFC, SRCS);

    const int BIG = 1 << 30;
    for (int l = 0; l < LLAYERS; l++) {
        const ushort* W1T = WT + l*16384;
        const ushort* W2T = WT + 49152  + l*49152;
        const ushort* UVT = WT + 196608 + l*32768;
        const ushort* A1T = WT + 294912 + l*32768;
        const ushort* A2T = WT + 393216 + l*49152;

        // HB = silu(S@w1+b1)  [bf16 out]
        k_mgemm<true,false,true,false><<<dim3(2,256), 128, 0, stream>>>(
            SBF, 128, nullptr, 0, BIG, W1T, 128, msg_b1 + (size_t)l*128,
            nullptr, 0, nullptr, 0, 0, HB, 128, 128);
        // PHIB = HB@w2+b2  [bf16 out]
        k_mgemm<false,false,true,false><<<dim3(6,256), 128, 0, stream>>>(
            HB, 128, nullptr, 0, BIG, W2T, 128, msg_b2 + (size_t)l*384,
            nullptr, 0, nullptr, 0, 0, PHIB, 384, 128);
        // message aggregation (in-place V update; VBFB = vout bf16)
        k_aggregate<<<8192, 192, 0, stream>>>(PHIB, VBFA, S, SBF, V, VBFB, RBF, UNITFC,
            SRCS, OFF, rbf_w + (size_t)l*20*384, rbf_b + (size_t)l*384);
        // UV | VV = vout @ [u|v]   [f32 out, col-split]
        k_mgemm<false,true,false,true><<<dim3(4,768), 128, 0, stream>>>(
            VBFB, 128, nullptr, 0, BIG, UVT, 128, nullptr,
            UV, 128, VV, 128, 128, nullptr, 0, 128);
        k_vvdot<<<4096, 256, 0, stream>>>(UV, VV, VVNB, DOT);
        // H2B = silu([S|VVN]@a1+b1)  [bf16 out, A split at K=128]
        k_mgemm<true,false,true,false><<<dim3(2,256), 128, 0, stream>>>(
            SBF, 128, VVNB, 128, 128, A1T, 256, upd_a1b + (size_t)l*128,
            nullptr, 0, nullptr, 0, 0, H2B, 128, 256);
        // ABUF = H2B@a2+b2  [f32 out]
        k_mgemm<false,true,false,false><<<dim3(6,256), 128, 0, stream>>>(
            H2B, 128, nullptr, 0, BIG, A2T, 128, upd_a2b + (size_t)l*384,
            ABUF, 384, nullptr, 0, 0, nullptr, 0, 128);
        k_update<<<4096, 256, 0, stream>>>(S, SBF, V, VBFA, ABUF, UV, DOT);
    }

    // readout: H = silu(S@out_w1+b1) [f32]; AOUT = H.w2+b2; molecule sum
    k_mgemm<true,true,false,false><<<dim3(2,256), 128, 0, stream>>>(
        SBF, 128, nullptr, 0, BIG, WT + 540672, 128, out_b1,
        H, 128, nullptr, 0, 0, nullptr, 0, 128);
    k_dot<<<2048, 256, 0, stream>>>(H, out_w2, out_b2, AOUT);
    hipMemsetAsync(d_out, 0, N_MOL * sizeof(float), stream);
    k_molsum<<<32, 256, 0, stream>>>(AOUT, mol, (float*)d_out);
}

// Round 7
// 720.411 us; speedup vs baseline: 1.6280x; 1.2607x over previous
//
#include <hip/hip_runtime.h>
#include <hip/hip_bf16.h>
#include <math.h>

#define N_ATOMS 8192
#define N_EDGES 262144
#define N_MOL   128
#define FDIM    128
#define RDIM    20
#define LLAYERS 3
#define CUTOFF  5.0f
#define EPSV    1e-8f
#define PI_F    3.14159265358979323846f

typedef __attribute__((ext_vector_type(8))) short bf16x8;
typedef __attribute__((ext_vector_type(4))) float f32x4;

__device__ __forceinline__ ushort f2bf(float x) {
    uint b = __float_as_uint(x);
    return (ushort)((b + 0x7fffu + ((b >> 16) & 1u)) >> 16);
}

// ---------------- weight convert+transpose (f32 KxN -> bf16 NxK), all at once ----------------
__global__ void k_wconv(const float* __restrict__ w1, const float* __restrict__ w2,
                        const float* __restrict__ uu, const float* __restrict__ uvw,
                        const float* __restrict__ a1, const float* __restrict__ a2,
                        const float* __restrict__ ow1, ushort* __restrict__ WT) {
    int i = blockIdx.x * 256 + threadIdx.x;  // < 557056
    float v;
    if (i < 49152) {                          // W1T
        int idx = i; int l = idx >> 14; idx &= 16383;
        int n = idx >> 7, k = idx & 127;
        v = w1[l*16384 + k*128 + n];
    } else if (i < 196608) {                  // W2T
        int idx = i - 49152; int l = idx / 49152; idx -= l * 49152;
        int n = idx >> 7, k = idx & 127;
        v = w2[l*49152 + k*384 + n];
    } else if (i < 294912) {                  // UVT (u cols 0-127, v cols 128-255)
        int idx = i - 196608; int l = idx >> 15; idx &= 32767;
        int n = idx >> 7, k = idx & 127;
        v = (n < 128) ? uu[l*16384 + k*128 + n] : uvw[l*16384 + k*128 + (n-128)];
    } else if (i < 393216) {                  // A1T (K=256)
        int idx = i - 294912; int l = idx >> 15; idx &= 32767;
        int n = idx >> 8, k = idx & 255;
        v = a1[l*32768 + k*128 + n];
    } else if (i < 540672) {                  // A2T
        int idx = i - 393216; int l = idx / 49152; idx -= l * 49152;
        int n = idx >> 7, k = idx & 127;
        v = a2[l*49152 + k*384 + n];
    } else {                                  // OW1T
        int idx = i - 540672;
        int n = idx >> 7, k = idx & 127;
        v = ow1[k*128 + n];
    }
    WT[i] = f2bf(v);
}

// ---------------- embed gather ----------------
__global__ void k_embed(const int* __restrict__ z, const float* __restrict__ embed,
                        float* __restrict__ S, ushort* __restrict__ SBF) {
    int i = blockIdx.x * 256 + threadIdx.x;
    int a = i >> 7, k = i & 127;
    float v = embed[(size_t)z[a] * FDIM + k];
    S[i] = v; SBF[i] = f2bf(v);
}

// ---------------- CSR build ----------------
__global__ void k_hist(const int* __restrict__ edst, int* __restrict__ CNT) {
    int e = blockIdx.x * 256 + threadIdx.x;
    if (e < N_EDGES) atomicAdd(&CNT[edst[e]], 1);
}

__global__ __launch_bounds__(1024) void k_scan(const int* __restrict__ CNT,
                                               int* __restrict__ OFF, int* __restrict__ CUR) {
    __shared__ int part[1024];
    int t = threadIdx.x;
    int loc[8];
    int run = 0;
    #pragma unroll
    for (int i = 0; i < 8; i++) { int c = CNT[t*8 + i]; loc[i] = run; run += c; }
    part[t] = run;
    __syncthreads();
    for (int off = 1; off < 1024; off <<= 1) {
        int v = 0;
        if (t >= off) v = part[t - off];
        __syncthreads();
        part[t] += v;
        __syncthreads();
    }
    int ebase = (t > 0) ? part[t-1] : 0;
    #pragma unroll
    for (int i = 0; i < 8; i++) { int o = ebase + loc[i]; OFF[t*8+i] = o; CUR[t*8+i] = o; }
    if (t == 1023) OFF[8192] = part[1023];
}

__global__ void k_pos(const int* __restrict__ edst, int* __restrict__ CUR,
                      int* __restrict__ POS) {
    int e = blockIdx.x * 256 + threadIdx.x;
    if (e < N_EDGES) POS[e] = atomicAdd(&CUR[edst[e]], 1);
}

// ---------------- edge geometry + rbf, written in CSR-sorted order ----------------
__global__ void k_edges(const float* __restrict__ pos, const int* __restrict__ esrc,
                        const int* __restrict__ edst, const int* __restrict__ POS,
                        float* __restrict__ RBF, float* __restrict__ UNITFC,
                        int* __restrict__ SRCS) {
    int e = blockIdx.x * 256 + threadIdx.x;
    if (e >= N_EDGES) return;
    int s = esrc[e], d = edst[e];
    int p = POS[e];
    float rx = pos[d*3+0] - pos[s*3+0];
    float ry = pos[d*3+1] - pos[s*3+1];
    float rz = pos[d*3+2] - pos[s*3+2];
    float dd = sqrtf(rx*rx + ry*ry + rz*rz + EPSV);
    float inv = 1.0f / dd;
    float fc = (dd < CUTOFF) ? 0.5f * (cosf(dd * (PI_F / CUTOFF)) + 1.0f) : 0.0f;
    float4 u4; u4.x = rx*inv; u4.y = ry*inv; u4.z = rz*inv; u4.w = fc;
    *(float4*)&UNITFC[(size_t)p*4] = u4;
    SRCS[p] = s;
    float rb[RDIM];
    #pragma unroll
    for (int r = 0; r < RDIM; r++) {
        float freq = (float)(r + 1) * (PI_F / CUTOFF);
        rb[r] = sinf(dd * freq) * inv;
    }
    float4* out = (float4*)&RBF[(size_t)p * RDIM];
    #pragma unroll
    for (int q = 0; q < 5; q++) {
        float4 o; o.x = rb[q*4]; o.y = rb[q*4+1]; o.z = rb[q*4+2]; o.w = rb[q*4+3];
        out[q] = o;
    }
}

// ---------------- bf16 MFMA GEMM (1-wave blocks for latency hiding) ----------------
// C = act(A @ BT^T + bias); A bf16 (M,K) row-major split at asplit; BT bf16 (N,K) row-major.
// Block = 64 threads = 1 wave; tile 16(M) x 64(N).
template<bool SILU, bool WF32, bool WB16, bool CSPLIT>
__global__ __launch_bounds__(64) void k_mgemm(
    const ushort* __restrict__ A, int lda, const ushort* __restrict__ A2, int lda2, int asplit,
    const ushort* __restrict__ BT, int ldbt, const float* __restrict__ bias,
    float* __restrict__ C, int ldc, float* __restrict__ C2, int ldc2, int csplit,
    ushort* __restrict__ CB, int ldcb, int K)
{
    int l = threadIdx.x;
    int bm = blockIdx.y * 16;
    int bn = blockIdx.x * 64;
    int lrow = l & 15, lk = (l >> 4) * 8;

    f32x4 acc[4] = {{0.f,0.f,0.f,0.f},{0.f,0.f,0.f,0.f},{0.f,0.f,0.f,0.f},{0.f,0.f,0.f,0.f}};
    for (int k0 = 0; k0 < K; k0 += 32) {
        int ka = k0 + lk;
        const ushort* Ap; int ldA;
        if (ka < asplit) { Ap = A; ldA = lda; } else { Ap = A2; ldA = lda2; ka -= asplit; }
        bf16x8 af = *(const bf16x8*)&Ap[(size_t)(bm + lrow) * ldA + ka];
        #pragma unroll
        for (int t = 0; t < 4; t++) {
            bf16x8 bfr = *(const bf16x8*)&BT[(size_t)(bn + t*16 + lrow) * ldbt + k0 + lk];
            acc[t] = __builtin_amdgcn_mfma_f32_16x16x32_bf16(af, bfr, acc[t], 0, 0, 0);
        }
    }
    #pragma unroll
    for (int t = 0; t < 4; t++) {
        int col = bn + t*16 + lrow;
        float bv = bias ? bias[col] : 0.0f;
        #pragma unroll
        for (int j = 0; j < 4; j++) {
            int row = bm + (l >> 4) * 4 + j;
            float val = acc[t][j] + bv;
            if (SILU) val = val / (1.0f + __expf(-val));
            if (WF32) {
                if (CSPLIT && col >= csplit) C2[(size_t)row * ldc2 + (col - csplit)] = val;
                else                         C [(size_t)row * ldc  + col] = val;
            }
            if (WB16) CB[(size_t)row * ldcb + col] = f2bf(val);
        }
    }
}

// ---------------- edge aggregation v5: CSR streams + group-of-4 gather pipeline ----------------
__global__ __launch_bounds__(192) void k_aggregate(
    const ushort* __restrict__ PHIB, const ushort* __restrict__ VBFA,
    float* __restrict__ S, ushort* __restrict__ SBF,
    float* __restrict__ V, ushort* __restrict__ VBFB,
    const float* __restrict__ RBF, const float* __restrict__ UNITFC,
    const int* __restrict__ SRCS, const int* __restrict__ OFF,
    const float* __restrict__ rbfw, const float* __restrict__ rbfb)
{
    int a = blockIdx.x;
    int tid = threadIdx.x;
    int g = tid >> 6;          // wave role: 0=ds, 1=v*dvv, 2=unit*dvs
    int c0 = 2 * (tid & 63);   // channel pair within section

    float2 w[RDIM];
    const float* wc = rbfw + g*128 + c0;
    #pragma unroll
    for (int r = 0; r < RDIM; r++) { w[r].x = wc[r*384]; w[r].y = wc[r*384 + 1]; }
    float2 bb; bb.x = rbfb[g*128 + c0]; bb.y = rbfb[g*128 + c0 + 1];

    __shared__ int sSrc[64];
    __shared__ float4 sRBF[320];
    __shared__ float4 sUFC[64];
    __shared__ float avs[3][128];

    int beg = OFF[a], end = OFF[a + 1];
    float2 d; d.x = 0.f; d.y = 0.f;
    float2 A0, A1, A2v;
    A0.x=A0.y=A1.x=A1.y=A2v.x=A2v.y=0.f;

    for (int p0 = beg; p0 < end; p0 += 64) {
        int n = end - p0; if (n > 64) n = 64;
        __syncthreads();
        if (tid < n) sSrc[tid] = SRCS[p0 + tid];
        for (int i = tid; i < n; i += 192)
            sUFC[i] = *(const float4*)(UNITFC + (size_t)(p0 + i) * 4);
        {
            const float4* rsrc = (const float4*)(RBF + (size_t)p0 * RDIM);
            for (int i = tid; i < n*5; i += 192) sRBF[i] = rsrc[i];
        }
        __syncthreads();

        uint phA[4], u0A[4], u1A[4], u2A[4];
        uint phB[4], u0B[4], u1B[4], u2B[4];

        auto grpLoad = [&](int base, uint* ph, uint* u0, uint* u1, uint* u2) {
            #pragma unroll
            for (int j = 0; j < 4; j++) {
                int q = base + j;
                int src = sSrc[(q < n) ? q : 0];
                size_t pb = (size_t)src * 384;
                ph[j] = *(const uint*)&PHIB[pb + g*128 + c0];
                if (g == 1) {
                    u0[j] = *(const uint*)&VBFA[pb + c0];
                    u1[j] = *(const uint*)&VBFA[pb + c0 + 128];
                    u2[j] = *(const uint*)&VBFA[pb + c0 + 256];
                }
            }
        };
        grpLoad(0, phA, u0A, u1A, u2A);
        for (int q0 = 0; q0 < n; q0 += 4) {
            if (q0 + 4 < n) grpLoad(q0 + 4, phB, u0B, u1B, u2B);
            #pragma unroll
            for (int j = 0; j < 4; j++) {
                int q = q0 + j;
                if (q >= n) break;
                float4 r0 = sRBF[q*5+0], r1 = sRBF[q*5+1], r2 = sRBF[q*5+2],
                       r3 = sRBF[q*5+3], r4 = sRBF[q*5+4];
                float4 ufc = sUFC[q];
                float2 f = bb;
                f.x += r0.x*w[0].x;   f.y += r0.x*w[0].y;
                f.x += r0.y*w[1].x;   f.y += r0.y*w[1].y;
                f.x += r0.z*w[2].x;   f.y += r0.z*w[2].y;
                f.x += r0.w*w[3].x;   f.y += r0.w*w[3].y;
                f.x += r1.x*w[4].x;   f.y += r1.x*w[4].y;
                f.x += r1.y*w[5].x;   f.y += r1.y*w[5].y;
                f.x += r1.z*w[6].x;   f.y += r1.z*w[6].y;
                f.x += r1.w*w[7].x;   f.y += r1.w*w[7].y;
                f.x += r2.x*w[8].x;   f.y += r2.x*w[8].y;
                f.x += r2.y*w[9].x;   f.y += r2.y*w[9].y;
                f.x += r2.z*w[10].x;  f.y += r2.z*w[10].y;
                f.x += r2.w*w[11].x;  f.y += r2.w*w[11].y;
                f.x += r3.x*w[12].x;  f.y += r3.x*w[12].y;
                f.x += r3.y*w[13].x;  f.y += r3.y*w[13].y;
                f.x += r3.z*w[14].x;  f.y += r3.z*w[14].y;
                f.x += r3.w*w[15].x;  f.y += r3.w*w[15].y;
                f.x += r4.x*w[16].x;  f.y += r4.x*w[16].y;
                f.x += r4.y*w[17].x;  f.y += r4.y*w[17].y;
                f.x += r4.z*w[18].x;  f.y += r4.z*w[18].y;
                f.x += r4.w*w[19].x;  f.y += r4.w*w[19].y;
                uint up = phA[j];
                float m0 = __uint_as_float(up << 16)        * (f.x * ufc.w);
                float m1 = __uint_as_float(up & 0xffff0000u) * (f.y * ufc.w);
                if (g == 0) {
                    d.x += m0; d.y += m1;
                } else if (g == 1) {
                    A0.x  += __uint_as_float(u0A[j] << 16)         * m0;
                    A0.y  += __uint_as_float(u0A[j] & 0xffff0000u) * m1;
                    A1.x  += __uint_as_float(u1A[j] << 16)         * m0;
                    A1.y  += __uint_as_float(u1A[j] & 0xffff0000u) * m1;
                    A2v.x += __uint_as_float(u2A[j] << 16)         * m0;
                    A2v.y += __uint_as_float(u2A[j] & 0xffff0000u) * m1;
                } else {
                    A0.x  += ufc.x * m0; A0.y  += ufc.x * m1;
                    A1.x  += ufc.y * m0; A1.y  += ufc.y * m1;
                    A2v.x += ufc.z * m0; A2v.y += ufc.z * m1;
                }
            }
            #pragma unroll
            for (int j = 0; j < 4; j++) {
                phA[j] = phB[j]; u0A[j] = u0B[j]; u1A[j] = u1B[j]; u2A[j] = u2B[j];
            }
        }
    }

    if (g == 1) {
        avs[0][c0] = A0.x;  avs[0][c0+1] = A0.y;
        avs[1][c0] = A1.x;  avs[1][c0+1] = A1.y;
        avs[2][c0] = A2v.x; avs[2][c0+1] = A2v.y;
    }
    __syncthreads();
    if (g == 0) {
        size_t sb = (size_t)a*128 + c0;
        float2 s2 = *(float2*)&S[sb];
        s2.x += d.x; s2.y += d.y;
        *(float2*)&S[sb] = s2;
        SBF[sb] = f2bf(s2.x); SBF[sb+1] = f2bf(s2.y);
    } else if (g == 2) {
        float own0[3] = {A0.x, A1.x, A2v.x};
        float own1[3] = {A0.y, A1.y, A2v.y};
        #pragma unroll
        for (int c = 0; c < 3; c++) {
            size_t vb = (size_t)a*384 + c*128 + c0;
            float2 vi = *(const float2*)&V[vb];
            vi.x += avs[c][c0]     + own0[c];
            vi.y += avs[c][c0 + 1] + own1[c];
            *(float2*)&V[vb] = vi;
            VBFB[vb] = f2bf(vi.x); VBFB[vb+1] = f2bf(vi.y);
        }
    }
}

// ---------------- vv-norm + <uv,vv> ----------------
__global__ void k_vvdot(const float* __restrict__ UV, const float* __restrict__ VV,
                        ushort* __restrict__ VVNB, float* __restrict__ DOT) {
    int i = blockIdx.x * 256 + threadIdx.x;
    int a = i >> 7, k = i & 127;
    size_t b = (size_t)a * 384 + k;
    float u0 = UV[b], u1 = UV[b+128], u2 = UV[b+256];
    float v0 = VV[b], v1 = VV[b+128], v2 = VV[b+256];
    VVNB[i] = f2bf(sqrtf(v0*v0 + v1*v1 + v2*v2 + EPSV));
    DOT[i] = u0*v0 + u1*v1 + u2*v2;
}

// ---------------- s,v update epilogue (+ bf16 shadows) ----------------
__global__ void k_update(float* __restrict__ S, ushort* __restrict__ SBF,
                         float* __restrict__ V, ushort* __restrict__ VBFA,
                         const float* __restrict__ Abuf, const float* __restrict__ UV,
                         const float* __restrict__ DOT) {
    int i = blockIdx.x * 256 + threadIdx.x;
    int a = i >> 7, k = i & 127;
    size_t b = (size_t)a * 384 + k;
    float a_vv = Abuf[b], a_sv = Abuf[b+128], a_ss = Abuf[b+256];
    float sn = S[i] + a_ss + a_sv * DOT[i];
    S[i] = sn; SBF[i] = f2bf(sn);
    float n0 = V[b]       + a_vv * UV[b];
    float n1 = V[b + 128] + a_vv * UV[b + 128];
    float n2 = V[b + 256] + a_vv * UV[b + 256];
    V[b] = n0; V[b + 128] = n1; V[b + 256] = n2;
    VBFA[b] = f2bf(n0); VBFA[b + 128] = f2bf(n1); VBFA[b + 256] = f2bf(n2);
}

// ---------------- readout dot ----------------
__global__ __launch_bounds__(256) void k_dot(const float* __restrict__ H,
                                             const float* __restrict__ w2,
                                             const float* __restrict__ b2v,
                                             float* __restrict__ AOUT) {
    int lane = threadIdx.x & 63;
    int wv = threadIdx.x >> 6;
    int a = blockIdx.x * 4 + wv;
    const float* h = &H[(size_t)a * 128];
    float p = h[lane] * w2[lane] + h[64 + lane] * w2[64 + lane];
    #pragma unroll
    for (int off = 32; off > 0; off >>= 1) p += __shfl_down(p, off);
    if (lane == 0) AOUT[a] = p + b2v[0];
}

// ---------------- per-molecule sum ----------------
__global__ void k_molsum(const float* __restrict__ AOUT, const int* __restrict__ mol,
                         float* __restrict__ out) {
    __shared__ float acc[N_MOL];
    int t = threadIdx.x;
    if (t < N_MOL) acc[t] = 0.f;
    __syncthreads();
    for (int i = blockIdx.x * 256 + t; i < N_ATOMS; i += 256 * 32)
        atomicAdd(&acc[mol[i]], AOUT[i]);
    __syncthreads();
    if (t < N_MOL) atomicAdd(&out[t], acc[t]);
}

extern "C" void kernel_launch(void* const* d_in, const int* in_sizes, int n_in,
                              void* d_out, int out_size, void* d_ws, size_t ws_size,
                              hipStream_t stream) {
    const int*   z      = (const int*)d_in[0];
    const float* pos    = (const float*)d_in[1];
    const int*   esrc   = (const int*)d_in[2];
    const int*   edst   = (const int*)d_in[3];
    const int*   mol    = (const int*)d_in[4];
    const float* embed  = (const float*)d_in[5];
    const float* msg_w1 = (const float*)d_in[6];
    const float* msg_b1 = (const float*)d_in[7];
    const float* msg_w2 = (const float*)d_in[8];
    const float* msg_b2 = (const float*)d_in[9];
    const float* rbf_w  = (const float*)d_in[10];
    const float* rbf_b  = (const float*)d_in[11];
    const float* upd_u  = (const float*)d_in[12];
    const float* upd_v  = (const float*)d_in[13];
    const float* upd_a1 = (const float*)d_in[14];
    const float* upd_a1b= (const float*)d_in[15];
    const float* upd_a2 = (const float*)d_in[16];
    const float* upd_a2b= (const float*)d_in[17];
    const float* out_w1 = (const float*)d_in[18];
    const float* out_b1 = (const float*)d_in[19];
    const float* out_w2 = (const float*)d_in[20];
    const float* out_b2 = (const float*)d_in[21];

    float* ws = (float*)d_ws;
    float* S      = ws; ws += 1048576;     // 8192*128 f32
    float* V      = ws; ws += 3145728;     // 8192*3*128 f32 (in-place across layers)
    float* ABUF   = ws; ws += 3145728;     // a2-out f32; alias VV and readout-H
    float* UV     = ws; ws += 3145728;
    float* DOT    = ws; ws += 1048576;
    float* RBF    = ws; ws += 5242880;     // sorted, 262144*20
    float* UNITFC = ws; ws += 1048576;     // sorted, 262144*4
    float* AOUT   = ws; ws += 8192;
    ushort* PHIB  = (ushort*)ws; ws += 1572864;   // 8192*384
    ushort* VBFA  = (ushort*)ws; ws += 1572864;   // v bf16 (gather table)
    ushort* VBFB  = (ushort*)ws; ws += 1572864;   // vout bf16 (GEMM A)
    ushort* SBF   = (ushort*)ws; ws += 524288;    // 8192*128
    ushort* VVNB  = (ushort*)ws; ws += 524288;
    ushort* HB    = (ushort*)ws; ws += 524288;
    ushort* H2B   = (ushort*)ws; ws += 524288;
    ushort* WT    = (ushort*)ws; ws += 278528;    // 557056 bf16 weights
    int* CNT  = (int*)ws;
    int* OFF  = CNT + 8192;
    int* CUR  = OFF + 8193;
    int* POS  = CUR + 8192;
    int* SRCS = POS + N_EDGES;
    float* VV = ABUF;                  // lifetime-disjoint aliases
    float* H  = ABUF;

    hipMemsetAsync(V, 0, 3145728 * sizeof(float), stream);
    hipMemsetAsync(VBFA, 0, 3145728 * sizeof(ushort), stream);
    hipMemsetAsync(CNT, 0, 8192 * sizeof(int), stream);

    k_wconv<<<2176, 256, 0, stream>>>(msg_w1, msg_w2, upd_u, upd_v, upd_a1, upd_a2, out_w1, WT);
    k_embed<<<4096, 256, 0, stream>>>(z, embed, S, SBF);
    k_hist<<<1024, 256, 0, stream>>>(edst, CNT);
    k_scan<<<1, 1024, 0, stream>>>(CNT, OFF, CUR);
    k_pos<<<1024, 256, 0, stream>>>(edst, CUR, POS);
    k_edges<<<1024, 256, 0, stream>>>(pos, esrc, edst, POS, RBF, UNITFC, SRCS);

    const int BIG = 1 << 30;
    for (int l = 0; l < LLAYERS; l++) {
        const ushort* W1T = WT + l*16384;
        const ushort* W2T = WT + 49152  + l*49152;
        const ushort* UVT = WT + 196608 + l*32768;
        const ushort* A1T = WT + 294912 + l*32768;
        const ushort* A2T = WT + 393216 + l*49152;

        // HB = silu(S@w1+b1)  [bf16 out]
        k_mgemm<true,false,true,false><<<dim3(2,512), 64, 0, stream>>>(
            SBF, 128, nullptr, 0, BIG, W1T, 128, msg_b1 + (size_t)l*128,
            nullptr, 0, nullptr, 0, 0, HB, 128, 128);
        // PHIB = HB@w2+b2  [bf16 out]
        k_mgemm<false,false,true,false><<<dim3(6,512), 64, 0, stream>>>(
            HB, 128, nullptr, 0, BIG, W2T, 128, msg_b2 + (size_t)l*384,
            nullptr, 0, nullptr, 0, 0, PHIB, 384, 128);
        // message aggregation (in-place V update; VBFB = vout bf16)
        k_aggregate<<<8192, 192, 0, stream>>>(PHIB, VBFA, S, SBF, V, VBFB, RBF, UNITFC,
            SRCS, OFF, rbf_w + (size_t)l*20*384, rbf_b + (size_t)l*384);
        // UV | VV = vout @ [u|v]   [f32 out, col-split]
        k_mgemm<false,true,false,true><<<dim3(4,1536), 64, 0, stream>>>(
            VBFB, 128, nullptr, 0, BIG, UVT, 128, nullptr,
            UV, 128, VV, 128, 128, nullptr, 0, 128);
        k_vvdot<<<4096, 256, 0, stream>>>(UV, VV, VVNB, DOT);
        // H2B = silu([S|VVN]@a1+b1)  [bf16 out, A split at K=128]
        k_mgemm<true,false,true,false><<<dim3(2,512), 64, 0, stream>>>(
            SBF, 128, VVNB, 128, 128, A1T, 256, upd_a1b + (size_t)l*128,
            nullptr, 0, nullptr, 0, 0, H2B, 128, 256);
        // ABUF = H2B@a2+b2  [f32 out]
        k_mgemm<false,true,false,false><<<dim3(6,512), 64, 0, stream>>>(
            H2B, 128, nullptr, 0, BIG, A2T, 128, upd_a2b + (size_t)l*384,
            ABUF, 384, nullptr, 0, 0, nullptr, 0, 128);
        k_update<<<4096, 256, 0, stream>>>(S, SBF, V, VBFA, ABUF, UV, DOT);
    }

    // readout: H = silu(S@out_w1+b1) [f32]; AOUT = H.w2+b2; molecule sum
    k_mgemm<true,true,false,false><<<dim3(2,512), 64, 0, stream>>>(
        SBF, 128, nullptr, 0, BIG, WT + 540672, 128, out_b1,
        H, 128, nullptr, 0, 0, nullptr, 0, 128);
    k_dot<<<2048, 256, 0, stream>>>(H, out_w2, out_b2, AOUT);
    hipMemsetAsync(d_out, 0, N_MOL * sizeof(float), stream);
    k_molsum<<<32, 256, 0, stream>>>(AOUT, mol, (float*)d_out);
}